// Round 7
// baseline (533.958 us; speedup 1.0000x reference)
//
#include <hip/hip_runtime.h>
#include <hip/hip_fp16.h>
#include <math.h>

// GCN: out = D^-1/2 (A+I) D^-1/2 (x W^T) + b per layer, ReLU between layers.
// R1: multiblock scan. R2: fp16 G + gather ILP. R3: MFMA split-fp16 GEMM.
// R4/R5/R6: two-level counting-sort graph build (write-locality + occupancy).
// R7: XCD-affine column-chunked aggregation — split the 256B G row into 4
// 64B line-chunks; chunk c processed only by blocks with blockIdx%4==c
// (round-robin block->XCD => chunk lives on 2 XCDs, G fetch 102->26MB).
// Also: fewer launches (detect inlined, binbase computed locally, split_w x1).

typedef _Float16 f16x8 __attribute__((ext_vector_type(8)));
typedef float f32x4 __attribute__((ext_vector_type(4)));

#define NBIN 128
#define NB 512       // histogram/scatter blocks
#define WCAP 12288   // k_build LDS col-window entries (48 KB)

// ---------------- graph build ----------------

__device__ __forceinline__ int edge_at(const void* ei, int is64, long long idx) {
  if (is64) return (int)((const long long*)ei)[idx];
  return ((const int*)ei)[idx];
}

// per-block int64-layout detection: hi-words of first 256 values all zero
__device__ __forceinline__ int detect_is64(const int* ei32, int E, int* ldsflag, int tid) {
  if (tid == 0) *ldsflag = 0;
  __syncthreads();
  int lim = (E < 256) ? E : 256;
  if (tid < lim) {
    if (ei32[2 * tid + 1] != 0) atomicOr(ldsflag, 1);
  }
  __syncthreads();
  return (*ldsflag == 0) ? 1 : 0;
}

// pass A: per-block per-bin histogram -> bcnt[block][bin]
__global__ __launch_bounds__(512) void k_cnt2(const void* __restrict__ ei, int* __restrict__ bcnt,
                                              int E, int n, int W) {
  __shared__ int cnt[NBIN];
  __shared__ int f64;
  int t = threadIdx.x;
  int is64 = detect_is64((const int*)ei, E, &f64, t);
  if (t < NBIN) cnt[t] = 0;
  __syncthreads();
  int chunk = (E + NB - 1) / NB;
  int base = blockIdx.x * chunk;
  int end = base + chunk;
  if (end > E) end = E;
  for (int i = base + t; i < end; i += 512) {
    int s = edge_at(ei, is64, i);
    int v = edge_at(ei, is64, (long long)E + i);
    if ((unsigned)v < (unsigned)n && (unsigned)s < (unsigned)n) atomicAdd(&cnt[v / W], 1);
  }
  __syncthreads();
  if (t < NBIN) bcnt[blockIdx.x * NBIN + t] = cnt[t];
}

// pass B: per bin, exclusive scan over NB block-counts (in place) + bin total
__global__ __launch_bounds__(256) void k_scanb(int* __restrict__ bcnt, int* __restrict__ bintot) {
  __shared__ int buf[NB];
  int bin = blockIdx.x;
  int t = threadIdx.x;
  int a0 = bcnt[(size_t)t * NBIN + bin];
  int a1 = bcnt[(size_t)(t + 256) * NBIN + bin];
  buf[t] = a0;
  buf[t + 256] = a1;
  __syncthreads();
  for (int off = 1; off < NB; off <<= 1) {
    int x0 = (t >= off) ? buf[t - off] : 0;
    int x1 = (t + 256 >= off) ? buf[t + 256 - off] : 0;
    __syncthreads();
    buf[t] += x0;
    buf[t + 256] += x1;
    __syncthreads();
  }
  bcnt[(size_t)t * NBIN + bin] = buf[t] - a0;
  bcnt[(size_t)(t + 256) * NBIN + bin] = buf[t + 256] - a1;
  if (t == 255) bintot[bin] = buf[NB - 1];
}

// pass C: scatter edges into bin-grouped ebin; (block,bin) regions exclusive.
// binbase computed locally from bintot (saves a kernel + serialization).
__global__ __launch_bounds__(512) void k_scat(const void* __restrict__ ei, const int* __restrict__ bintot,
                                              const int* __restrict__ bcnt, uint2* __restrict__ ebin,
                                              int E, int n, int W) {
  __shared__ int f64;
  __shared__ int sb[NBIN];
  __shared__ int cur[NBIN];
  int t = threadIdx.x;
  int is64 = detect_is64((const int*)ei, E, &f64, t);
  if (t < NBIN) sb[t] = bintot[t];
  __syncthreads();
  for (int off = 1; off < NBIN; off <<= 1) {
    int x = 0;
    if (t < NBIN && t >= off) x = sb[t - off];
    __syncthreads();
    if (t < NBIN) sb[t] += x;
    __syncthreads();
  }
  if (t < NBIN) cur[t] = sb[t] - bintot[t] + bcnt[blockIdx.x * NBIN + t];
  __syncthreads();
  int chunk = (E + NB - 1) / NB;
  int base = blockIdx.x * chunk;
  int end = base + chunk;
  if (end > E) end = E;
  for (int i = base + t; i < end; i += 512) {
    int s = edge_at(ei, is64, i);
    int v = edge_at(ei, is64, (long long)E + i);
    if ((unsigned)v < (unsigned)n && (unsigned)s < (unsigned)n) {
      int pos = atomicAdd(&cur[v / W], 1);
      ebin[pos] = make_uint2((unsigned)s, (unsigned)v);
    }
  }
}

// per bin: deg hist -> dinv, LDS scan -> row_ptr, LDS window scatter -> col
__global__ __launch_bounds__(256) void k_build(const uint2* __restrict__ ebin, const int* __restrict__ bintot,
                                               int* __restrict__ row_ptr, float* __restrict__ dinv,
                                               int* __restrict__ col, int n, int W) {
  __shared__ int hist[512];
  __shared__ int scanBuf[512];
  __shared__ int sb[NBIN];
  __shared__ unsigned int win[WCAP];
  int t = threadIdx.x;
  int b = blockIdx.x;
  // local exclusive binbase from bintot
  if (t < NBIN) sb[t] = bintot[t];
  __syncthreads();
  for (int off = 1; off < NBIN; off <<= 1) {
    int x = 0;
    if (t < NBIN && t >= off) x = sb[t - off];
    __syncthreads();
    if (t < NBIN) sb[t] += x;
    __syncthreads();
  }
  int ebase = sb[b] - bintot[b];
  int ecnt = bintot[b];
  int etotal = sb[NBIN - 1];

  int v0 = b * W;
  int v1 = v0 + W;
  if (v1 > n) v1 = n;
  int nloc = v1 - v0;
  if (nloc <= 0) {
    if (b == NBIN - 1 && t == 0) row_ptr[n] = etotal;
    return;
  }

  for (int i = t; i < 512; i += 256) { hist[i] = 0; scanBuf[i] = 0; }
  __syncthreads();
  for (int j = t; j < ecnt; j += 256) {
    uint2 e = ebin[ebase + j];
    atomicAdd(&hist[(int)e.y - v0], 1);
  }
  __syncthreads();
  for (int i = t; i < nloc; i += 256) {
    scanBuf[i] = hist[i];
    dinv[v0 + i] = 1.0f / sqrtf((float)(hist[i] + 1));  // +1 self-loop
  }
  __syncthreads();
  int i1 = t, i2 = t + 256;
  for (int off = 1; off < 512; off <<= 1) {
    int a = (i1 >= off) ? scanBuf[i1 - off] : 0;
    int c = (i2 >= off) ? scanBuf[i2 - off] : 0;
    __syncthreads();
    scanBuf[i1] += a;
    scanBuf[i2] += c;
    __syncthreads();
  }
  for (int i = t; i < nloc; i += 256) row_ptr[v0 + i] = ebase + scanBuf[i] - hist[i];
  if (b == NBIN - 1 && t == 0) row_ptr[n] = etotal;
  __syncthreads();
  for (int i = t; i < nloc; i += 256) hist[i] = scanBuf[i] - hist[i];  // cursor
  __syncthreads();
  if (ecnt <= WCAP) {
    for (int j = t; j < ecnt; j += 256) {
      uint2 e = ebin[ebase + j];
      int pos = atomicAdd(&hist[(int)e.y - v0], 1);
      win[pos] = e.x;
    }
    __syncthreads();
    for (int j = t; j < ecnt; j += 256) col[ebase + j] = (int)win[j];  // coalesced
  } else {
    for (int j = t; j < ecnt; j += 256) {
      uint2 e = ebin[ebase + j];
      int pos = atomicAdd(&hist[(int)e.y - v0], 1);
      col[ebase + pos] = (int)e.x;
    }
  }
}

// ---------------- fp32 -> (h, r) fp16 splits ----------------

__global__ __launch_bounds__(256) void k_split_x(const float* __restrict__ X, unsigned int* __restrict__ Xh,
                                                 unsigned int* __restrict__ Xr, int n2) {
  int i = blockIdx.x * 256 + threadIdx.x;
  if (i >= n2) return;
  float2 v = ((const float2*)X)[i];
  __half hx = __float2half(v.x), hy = __float2half(v.y);
  float rx = v.x - __half2float(hx), ry = v.y - __half2float(hy);
  __half rxh = __float2half(rx), ryh = __float2half(ry);
  Xh[i] = ((unsigned int)*(unsigned short*)&hy << 16) | *(unsigned short*)&hx;
  Xr[i] = ((unsigned int)*(unsigned short*)&ryh << 16) | *(unsigned short*)&rxh;
}

// all 5 weights in one launch; wh/wr flat at l*16384 + off
__global__ __launch_bounds__(256) void k_split_wall(const float* __restrict__ W0, const float* __restrict__ W1,
                                                    const float* __restrict__ W2, const float* __restrict__ W3,
                                                    const float* __restrict__ W4, unsigned short* __restrict__ Wh,
                                                    unsigned short* __restrict__ Wr, int total) {
  int i = blockIdx.x * 256 + threadIdx.x;
  if (i >= total) return;
  const float* src;
  int off;
  if (i < 65536) {
    int l = i >> 14;
    off = i & 16383;
    src = (l == 0) ? W0 : (l == 1) ? W1 : (l == 2) ? W2 : W3;
  } else {
    off = i - 65536;
    src = W4;
  }
  float v = src[off];
  __half h = __float2half(v);
  float r = v - __half2float(h);
  __half rh = __float2half(r);
  Wh[i] = *(unsigned short*)&h;
  Wr[i] = *(unsigned short*)&rh;
}

// ---------------- MFMA GEMM: G[n,DO] = fp16( dinv * ((Xh+Xr) @ (Wh+Wr)^T) ) ----------------

template <int DO>
__global__ __launch_bounds__(256) void gemm_mfma(const unsigned short* __restrict__ Xh,
                                                 const unsigned short* __restrict__ Xr,
                                                 const unsigned short* __restrict__ Wh,
                                                 const unsigned short* __restrict__ Wr,
                                                 const float* __restrict__ dinv, __half* __restrict__ G, int n) {
  constexpr int NCG = DO / 16;
  __shared__ unsigned short sWh[DO * 128];
  __shared__ unsigned short sWr[DO * 128];
  const int tid = threadIdx.x;

#pragma unroll
  for (int it = 0; it < DO / 16; ++it) {
    int t = it * 256 + tid;
    int row = t >> 4, ch = t & 15;
    int sch = ch ^ (row & 7);
    const uint4* gh = (const uint4*)&Wh[(size_t)t * 8];
    const uint4* gr = (const uint4*)&Wr[(size_t)t * 8];
    *(uint4*)&sWh[row * 128 + sch * 8] = *gh;
    *(uint4*)&sWr[row * 128 + sch * 8] = *gr;
  }

  const int wv = tid >> 6;
  const int l = tid & 63;
  const int m = l & 15;
  const int ks = l >> 4;
  const int gr0 = blockIdx.x * 64 + wv * 16;
  const int arow = gr0 + m;

  f16x8 ah[4], ar[4];
  const f16x8 z8 = {0, 0, 0, 0, 0, 0, 0, 0};
#pragma unroll
  for (int kb = 0; kb < 4; ++kb) {
    int koff = kb * 32 + ks * 8;
    if (arow < n) {
      ah[kb] = *(const f16x8*)&Xh[(size_t)arow * 128 + koff];
      ar[kb] = *(const f16x8*)&Xr[(size_t)arow * 128 + koff];
    } else {
      ah[kb] = z8;
      ar[kb] = z8;
    }
  }

  f32x4 acc[NCG];
#pragma unroll
  for (int c = 0; c < NCG; ++c) acc[c] = {0.f, 0.f, 0.f, 0.f};

  __syncthreads();

#pragma unroll
  for (int kb = 0; kb < 4; ++kb) {
    int ch = (kb * 4 + ks) ^ (m & 7);
#pragma unroll
    for (int c = 0; c < NCG; ++c) {
      int brow = c * 16 + m;
      f16x8 bh = *(const f16x8*)&sWh[brow * 128 + ch * 8];
      f16x8 br = *(const f16x8*)&sWr[brow * 128 + ch * 8];
      acc[c] = __builtin_amdgcn_mfma_f32_16x16x32_f16(ah[kb], bh, acc[c], 0, 0, 0);
      acc[c] = __builtin_amdgcn_mfma_f32_16x16x32_f16(ah[kb], br, acc[c], 0, 0, 0);
      acc[c] = __builtin_amdgcn_mfma_f32_16x16x32_f16(ar[kb], bh, acc[c], 0, 0, 0);
    }
  }

  int r0 = gr0 + ks * 4;
  float dv[4];
#pragma unroll
  for (int i = 0; i < 4; ++i) dv[i] = (r0 + i < n) ? dinv[r0 + i] : 0.f;
#pragma unroll
  for (int c = 0; c < NCG; ++c) {
#pragma unroll
    for (int i = 0; i < 4; ++i) {
      int row = r0 + i;
      if (row < n) G[(size_t)row * DO + c * 16 + m] = __float2half(dv[i] * acc[c][i]);
    }
  }
}

// ---------------- aggregation ----------------

__device__ __forceinline__ float2 h2f(unsigned int u) {
  __half2 h = *(__half2*)&u;
  return __half22float2(h);
}

// R7: XCD-affine column-chunked aggregate for D=128.
// blockIdx = tile*4 + c; chunk c covers uints [c*16, c*16+16) = one 64B line
// of each G row. Round-robin block->XCD puts chunk c on XCDs {c, c+4} only.
// Wave: 4 edge-slots (q) x 16 cols (r); shfl_xor(16,32) reduces over q.
__global__ __launch_bounds__(256) void aggregate128c(const unsigned int* __restrict__ G,
                                                     const float* __restrict__ dinv,
                                                     const float* __restrict__ bias, const int* __restrict__ rp,
                                                     const int* __restrict__ col, unsigned int* __restrict__ Yh,
                                                     unsigned int* __restrict__ Yr, int n) {
  const int c = blockIdx.x & 3;
  const int tile = blockIdx.x >> 2;
  const int wv = threadIdx.x >> 6, lane = threadIdx.x & 63;
  const int q = lane >> 4, r = lane & 15;
  const int co = c * 16 + r;
  const int vbase = tile * 32 + wv * 8;
  for (int k = 0; k < 8; ++k) {
    int v = vbase + k;
    if (v >= n) break;
    int s = rp[v], e = rp[v + 1];
    float2 acc = make_float2(0.f, 0.f);
    if (q == 0) acc = h2f(G[(size_t)v * 64 + co]);  // self-loop term
    int t = s;
    while (t < e) {
      int batch = e - t;
      if (batch > 64) batch = 64;
      int ci = col[t + (lane < batch ? lane : batch - 1)];
      for (int j = 0; j < batch; j += 4) {
        int jq = j + q;
        int u = __shfl(ci, jq < batch ? jq : batch - 1, 64);
        if (jq < batch) {
          float2 f = h2f(G[(size_t)u * 64 + co]);
          acc.x += f.x;
          acc.y += f.y;
        }
      }
      t += batch;
    }
    acc.x += __shfl_xor(acc.x, 16, 64);
    acc.y += __shfl_xor(acc.y, 16, 64);
    acc.x += __shfl_xor(acc.x, 32, 64);
    acc.y += __shfl_xor(acc.y, 32, 64);
    if (q == 0) {
      float dv = dinv[v];
      float2 bb = ((const float2*)bias)[co];
      float ox = fmaxf(fmaf(dv, acc.x, bb.x), 0.f);  // ReLU
      float oy = fmaxf(fmaf(dv, acc.y, bb.y), 0.f);
      __half hx = __float2half(ox), hy = __float2half(oy);
      float rx = ox - __half2float(hx), ry = oy - __half2float(hy);
      __half rxh = __float2half(rx), ryh = __float2half(ry);
      size_t o = (size_t)v * 64 + co;
      Yh[o] = ((unsigned int)*(unsigned short*)&hy << 16) | *(unsigned short*)&hx;
      Yr[o] = ((unsigned int)*(unsigned short*)&ryh << 16) | *(unsigned short*)&rxh;
    }
  }
}

__global__ __launch_bounds__(256) void aggregate64(const unsigned short* __restrict__ G, const float* __restrict__ dinv,
                                                   const float* __restrict__ bias, const int* __restrict__ rp,
                                                   const int* __restrict__ col, float* __restrict__ Y, int n) {
  int v = (int)((blockIdx.x * 256 + threadIdx.x) >> 6);
  int lane = threadIdx.x & 63;
  if (v >= n) return;
  int s = rp[v], e = rp[v + 1];
  float a0 = __half2float(*(const __half*)&G[(size_t)v * 64 + lane]);
  float a1 = 0.f, a2 = 0.f, a3 = 0.f;
  int t = s;
  while (t < e) {
    int batch = e - t;
    if (batch > 64) batch = 64;
    int ci = col[t + (lane < batch ? lane : batch - 1)];
    int j = 0;
    for (; j + 4 <= batch; j += 4) {
      int u0 = __shfl(ci, j, 64), u1 = __shfl(ci, j + 1, 64);
      int u2 = __shfl(ci, j + 2, 64), u3 = __shfl(ci, j + 3, 64);
      unsigned short g0 = G[(size_t)u0 * 64 + lane];
      unsigned short g1 = G[(size_t)u1 * 64 + lane];
      unsigned short g2 = G[(size_t)u2 * 64 + lane];
      unsigned short g3 = G[(size_t)u3 * 64 + lane];
      a0 += __half2float(*(const __half*)&g0);
      a1 += __half2float(*(const __half*)&g1);
      a2 += __half2float(*(const __half*)&g2);
      a3 += __half2float(*(const __half*)&g3);
    }
    for (; j < batch; ++j) {
      int u = __shfl(ci, j, 64);
      unsigned short g = G[(size_t)u * 64 + lane];
      a0 += __half2float(*(const __half*)&g);
    }
    t += batch;
  }
  float sum = (a0 + a1) + (a2 + a3);
  Y[(size_t)v * 64 + lane] = fmaf(dinv[v], sum, bias[lane]);
}

// ---------------- launch ----------------

extern "C" void kernel_launch(void* const* d_in, const int* in_sizes, int n_in,
                              void* d_out, int out_size, void* d_ws, size_t ws_size,
                              hipStream_t stream) {
  const float* x = (const float*)d_in[0];
  const void* ei = d_in[1];
  const int N = in_sizes[0] / 128;
  const int E = in_sizes[1] / 2;
  const float* W[5] = {(const float*)d_in[2], (const float*)d_in[4], (const float*)d_in[6],
                       (const float*)d_in[8], (const float*)d_in[10]};
  const float* B[5] = {(const float*)d_in[3], (const float*)d_in[5], (const float*)d_in[7],
                       (const float*)d_in[9], (const float*)d_in[11]};
  const int Wbin = (N + NBIN - 1) / NBIN;

  char* p = (char*)d_ws;
  unsigned short* xyh = (unsigned short*)p;  p += (size_t)N * 128 * 2;   // activations h
  unsigned short* xyr = (unsigned short*)p;  p += (size_t)N * 128 * 2;   // activations r
  __half* g = (__half*)p;                    p += (size_t)N * 128 * 2;   // post-GEMM dinv.*h
  uint2* ebin = (uint2*)g;                   // ALIAS: ebin dead before first gemm writes g
  unsigned short* wh = (unsigned short*)p;   p += (size_t)5 * 16384 * 2;
  unsigned short* wr = (unsigned short*)p;   p += (size_t)5 * 16384 * 2;
  float* dinv = (float*)p;                   p += (size_t)N * 4;
  int* col = (int*)p;                        p += (size_t)E * 4;
  int* row_ptr = (int*)p;                    p += (size_t)(N + 1) * 4;
  int* bcnt = (int*)p;                       p += (size_t)NB * NBIN * 4;
  int* bintot = (int*)p;                     p += NBIN * 4;

  k_cnt2<<<NB, 512, 0, stream>>>(ei, bcnt, E, N, Wbin);
  k_scanb<<<NBIN, 256, 0, stream>>>(bcnt, bintot);
  k_scat<<<NB, 512, 0, stream>>>(ei, bintot, bcnt, ebin, E, N, Wbin);
  k_build<<<NBIN, 256, 0, stream>>>(ebin, bintot, row_ptr, dinv, col, N, Wbin);

  k_split_x<<<(N * 64 + 255) / 256, 256, 0, stream>>>(x, (unsigned int*)xyh, (unsigned int*)xyr, N * 64);
  k_split_wall<<<(73728 + 255) / 256, 256, 0, stream>>>(W[0], W[1], W[2], W[3], W[4], wh, wr, 73728);

  const int gb = (N + 63) / 64;
  const int acb = 4 * ((N + 31) / 32);
  const int ab = (N * 64 + 255) / 256;

  for (int l = 0; l < 4; ++l) {
    gemm_mfma<128><<<gb, 256, 0, stream>>>(xyh, xyr, wh + l * 16384, wr + l * 16384, dinv, g, N);
    aggregate128c<<<acb, 256, 0, stream>>>((const unsigned int*)g, dinv, B[l], row_ptr, col,
                                           (unsigned int*)xyh, (unsigned int*)xyr, N);
  }
  gemm_mfma<64><<<gb, 256, 0, stream>>>(xyh, xyr, wh + 4 * 16384, wr + 4 * 16384, dinv, g, N);
  aggregate64<<<ab, 256, 0, stream>>>((const unsigned short*)g, dinv, B[4], row_ptr, col, (float*)d_out, N);
}

// Round 8
// 303.181 us; speedup vs baseline: 1.7612x; 1.7612x over previous
//
#include <hip/hip_runtime.h>
#include <hip/hip_fp16.h>
#include <math.h>

// GCN: out = D^-1/2 (A+I) D^-1/2 (x W^T) + b per layer, ReLU between layers.
// R1: multiblock scan. R2: fp16 G + gather ILP. R3: MFMA split-fp16 GEMM.
// R4/R5/R6: two-level counting-sort graph build. R7 FAILED: column-chunked
// "XCD-affine" aggregate raised fetch (117MB) + VALU 3x — blockIdx%4 is not
// an XCD partition; reverted. R8: R6 aggregate + ILP-8 gather chains; keep
// R7's launch reductions (inlined detect, local binbase, single split_w).

typedef _Float16 f16x8 __attribute__((ext_vector_type(8)));
typedef float f32x4 __attribute__((ext_vector_type(4)));

#define NBIN 128
#define NB 512       // histogram/scatter blocks
#define WCAP 12288   // k_build LDS col-window entries (48 KB)

// ---------------- graph build ----------------

__device__ __forceinline__ int edge_at(const void* ei, int is64, long long idx) {
  if (is64) return (int)((const long long*)ei)[idx];
  return ((const int*)ei)[idx];
}

// per-block int64-layout detection: hi-words of first 256 values all zero
__device__ __forceinline__ int detect_is64(const int* ei32, int E, int* ldsflag, int tid) {
  if (tid == 0) *ldsflag = 0;
  __syncthreads();
  int lim = (E < 256) ? E : 256;
  if (tid < lim) {
    if (ei32[2 * tid + 1] != 0) atomicOr(ldsflag, 1);
  }
  __syncthreads();
  return (*ldsflag == 0) ? 1 : 0;
}

// pass A: per-block per-bin histogram -> bcnt[block][bin]
__global__ __launch_bounds__(512) void k_cnt2(const void* __restrict__ ei, int* __restrict__ bcnt,
                                              int E, int n, int W) {
  __shared__ int cnt[NBIN];
  __shared__ int f64;
  int t = threadIdx.x;
  int is64 = detect_is64((const int*)ei, E, &f64, t);
  if (t < NBIN) cnt[t] = 0;
  __syncthreads();
  int chunk = (E + NB - 1) / NB;
  int base = blockIdx.x * chunk;
  int end = base + chunk;
  if (end > E) end = E;
  for (int i = base + t; i < end; i += 512) {
    int s = edge_at(ei, is64, i);
    int v = edge_at(ei, is64, (long long)E + i);
    if ((unsigned)v < (unsigned)n && (unsigned)s < (unsigned)n) atomicAdd(&cnt[v / W], 1);
  }
  __syncthreads();
  if (t < NBIN) bcnt[blockIdx.x * NBIN + t] = cnt[t];
}

// pass B: per bin, exclusive scan over NB block-counts (in place) + bin total
__global__ __launch_bounds__(256) void k_scanb(int* __restrict__ bcnt, int* __restrict__ bintot) {
  __shared__ int buf[NB];
  int bin = blockIdx.x;
  int t = threadIdx.x;
  int a0 = bcnt[(size_t)t * NBIN + bin];
  int a1 = bcnt[(size_t)(t + 256) * NBIN + bin];
  buf[t] = a0;
  buf[t + 256] = a1;
  __syncthreads();
  for (int off = 1; off < NB; off <<= 1) {
    int x0 = (t >= off) ? buf[t - off] : 0;
    int x1 = (t + 256 >= off) ? buf[t + 256 - off] : 0;
    __syncthreads();
    buf[t] += x0;
    buf[t + 256] += x1;
    __syncthreads();
  }
  bcnt[(size_t)t * NBIN + bin] = buf[t] - a0;
  bcnt[(size_t)(t + 256) * NBIN + bin] = buf[t + 256] - a1;
  if (t == 255) bintot[bin] = buf[NB - 1];
}

// pass C: scatter edges into bin-grouped ebin; (block,bin) regions exclusive.
__global__ __launch_bounds__(512) void k_scat(const void* __restrict__ ei, const int* __restrict__ bintot,
                                              const int* __restrict__ bcnt, uint2* __restrict__ ebin,
                                              int E, int n, int W) {
  __shared__ int f64;
  __shared__ int sb[NBIN];
  __shared__ int cur[NBIN];
  int t = threadIdx.x;
  int is64 = detect_is64((const int*)ei, E, &f64, t);
  if (t < NBIN) sb[t] = bintot[t];
  __syncthreads();
  for (int off = 1; off < NBIN; off <<= 1) {
    int x = 0;
    if (t < NBIN && t >= off) x = sb[t - off];
    __syncthreads();
    if (t < NBIN) sb[t] += x;
    __syncthreads();
  }
  if (t < NBIN) cur[t] = sb[t] - bintot[t] + bcnt[blockIdx.x * NBIN + t];
  __syncthreads();
  int chunk = (E + NB - 1) / NB;
  int base = blockIdx.x * chunk;
  int end = base + chunk;
  if (end > E) end = E;
  for (int i = base + t; i < end; i += 512) {
    int s = edge_at(ei, is64, i);
    int v = edge_at(ei, is64, (long long)E + i);
    if ((unsigned)v < (unsigned)n && (unsigned)s < (unsigned)n) {
      int pos = atomicAdd(&cur[v / W], 1);
      ebin[pos] = make_uint2((unsigned)s, (unsigned)v);
    }
  }
}

// per bin: deg hist -> dinv, LDS scan -> row_ptr, LDS window scatter -> col
__global__ __launch_bounds__(256) void k_build(const uint2* __restrict__ ebin, const int* __restrict__ bintot,
                                               int* __restrict__ row_ptr, float* __restrict__ dinv,
                                               int* __restrict__ col, int n, int W) {
  __shared__ int hist[512];
  __shared__ int scanBuf[512];
  __shared__ int sb[NBIN];
  __shared__ unsigned int win[WCAP];
  int t = threadIdx.x;
  int b = blockIdx.x;
  if (t < NBIN) sb[t] = bintot[t];
  __syncthreads();
  for (int off = 1; off < NBIN; off <<= 1) {
    int x = 0;
    if (t < NBIN && t >= off) x = sb[t - off];
    __syncthreads();
    if (t < NBIN) sb[t] += x;
    __syncthreads();
  }
  int ebase = sb[b] - bintot[b];
  int ecnt = bintot[b];
  int etotal = sb[NBIN - 1];

  int v0 = b * W;
  int v1 = v0 + W;
  if (v1 > n) v1 = n;
  int nloc = v1 - v0;
  if (nloc <= 0) {
    if (b == NBIN - 1 && t == 0) row_ptr[n] = etotal;
    return;
  }

  for (int i = t; i < 512; i += 256) { hist[i] = 0; scanBuf[i] = 0; }
  __syncthreads();
  for (int j = t; j < ecnt; j += 256) {
    uint2 e = ebin[ebase + j];
    atomicAdd(&hist[(int)e.y - v0], 1);
  }
  __syncthreads();
  for (int i = t; i < nloc; i += 256) {
    scanBuf[i] = hist[i];
    dinv[v0 + i] = 1.0f / sqrtf((float)(hist[i] + 1));  // +1 self-loop
  }
  __syncthreads();
  int i1 = t, i2 = t + 256;
  for (int off = 1; off < 512; off <<= 1) {
    int a = (i1 >= off) ? scanBuf[i1 - off] : 0;
    int c = (i2 >= off) ? scanBuf[i2 - off] : 0;
    __syncthreads();
    scanBuf[i1] += a;
    scanBuf[i2] += c;
    __syncthreads();
  }
  for (int i = t; i < nloc; i += 256) row_ptr[v0 + i] = ebase + scanBuf[i] - hist[i];
  if (b == NBIN - 1 && t == 0) row_ptr[n] = etotal;
  __syncthreads();
  for (int i = t; i < nloc; i += 256) hist[i] = scanBuf[i] - hist[i];  // cursor
  __syncthreads();
  if (ecnt <= WCAP) {
    for (int j = t; j < ecnt; j += 256) {
      uint2 e = ebin[ebase + j];
      int pos = atomicAdd(&hist[(int)e.y - v0], 1);
      win[pos] = e.x;
    }
    __syncthreads();
    for (int j = t; j < ecnt; j += 256) col[ebase + j] = (int)win[j];  // coalesced
  } else {
    for (int j = t; j < ecnt; j += 256) {
      uint2 e = ebin[ebase + j];
      int pos = atomicAdd(&hist[(int)e.y - v0], 1);
      col[ebase + pos] = (int)e.x;
    }
  }
}

// ---------------- fp32 -> (h, r) fp16 splits ----------------

__global__ __launch_bounds__(256) void k_split_x(const float* __restrict__ X, unsigned int* __restrict__ Xh,
                                                 unsigned int* __restrict__ Xr, int n2) {
  int i = blockIdx.x * 256 + threadIdx.x;
  if (i >= n2) return;
  float2 v = ((const float2*)X)[i];
  __half hx = __float2half(v.x), hy = __float2half(v.y);
  float rx = v.x - __half2float(hx), ry = v.y - __half2float(hy);
  __half rxh = __float2half(rx), ryh = __float2half(ry);
  Xh[i] = ((unsigned int)*(unsigned short*)&hy << 16) | *(unsigned short*)&hx;
  Xr[i] = ((unsigned int)*(unsigned short*)&ryh << 16) | *(unsigned short*)&rxh;
}

__global__ __launch_bounds__(256) void k_split_wall(const float* __restrict__ W0, const float* __restrict__ W1,
                                                    const float* __restrict__ W2, const float* __restrict__ W3,
                                                    const float* __restrict__ W4, unsigned short* __restrict__ Wh,
                                                    unsigned short* __restrict__ Wr, int total) {
  int i = blockIdx.x * 256 + threadIdx.x;
  if (i >= total) return;
  const float* src;
  int off;
  if (i < 65536) {
    int l = i >> 14;
    off = i & 16383;
    src = (l == 0) ? W0 : (l == 1) ? W1 : (l == 2) ? W2 : W3;
  } else {
    off = i - 65536;
    src = W4;
  }
  float v = src[off];
  __half h = __float2half(v);
  float r = v - __half2float(h);
  __half rh = __float2half(r);
  Wh[i] = *(unsigned short*)&h;
  Wr[i] = *(unsigned short*)&rh;
}

// ---------------- MFMA GEMM: G[n,DO] = fp16( dinv * ((Xh+Xr) @ (Wh+Wr)^T) ) ----------------

template <int DO>
__global__ __launch_bounds__(256) void gemm_mfma(const unsigned short* __restrict__ Xh,
                                                 const unsigned short* __restrict__ Xr,
                                                 const unsigned short* __restrict__ Wh,
                                                 const unsigned short* __restrict__ Wr,
                                                 const float* __restrict__ dinv, __half* __restrict__ G, int n) {
  constexpr int NCG = DO / 16;
  __shared__ unsigned short sWh[DO * 128];
  __shared__ unsigned short sWr[DO * 128];
  const int tid = threadIdx.x;

#pragma unroll
  for (int it = 0; it < DO / 16; ++it) {
    int t = it * 256 + tid;
    int row = t >> 4, ch = t & 15;
    int sch = ch ^ (row & 7);
    const uint4* gh = (const uint4*)&Wh[(size_t)t * 8];
    const uint4* gr = (const uint4*)&Wr[(size_t)t * 8];
    *(uint4*)&sWh[row * 128 + sch * 8] = *gh;
    *(uint4*)&sWr[row * 128 + sch * 8] = *gr;
  }

  const int wv = tid >> 6;
  const int l = tid & 63;
  const int m = l & 15;
  const int ks = l >> 4;
  const int gr0 = blockIdx.x * 64 + wv * 16;
  const int arow = gr0 + m;

  f16x8 ah[4], ar[4];
  const f16x8 z8 = {0, 0, 0, 0, 0, 0, 0, 0};
#pragma unroll
  for (int kb = 0; kb < 4; ++kb) {
    int koff = kb * 32 + ks * 8;
    if (arow < n) {
      ah[kb] = *(const f16x8*)&Xh[(size_t)arow * 128 + koff];
      ar[kb] = *(const f16x8*)&Xr[(size_t)arow * 128 + koff];
    } else {
      ah[kb] = z8;
      ar[kb] = z8;
    }
  }

  f32x4 acc[NCG];
#pragma unroll
  for (int c = 0; c < NCG; ++c) acc[c] = {0.f, 0.f, 0.f, 0.f};

  __syncthreads();

#pragma unroll
  for (int kb = 0; kb < 4; ++kb) {
    int ch = (kb * 4 + ks) ^ (m & 7);
#pragma unroll
    for (int c = 0; c < NCG; ++c) {
      int brow = c * 16 + m;
      f16x8 bh = *(const f16x8*)&sWh[brow * 128 + ch * 8];
      f16x8 br = *(const f16x8*)&sWr[brow * 128 + ch * 8];
      acc[c] = __builtin_amdgcn_mfma_f32_16x16x32_f16(ah[kb], bh, acc[c], 0, 0, 0);
      acc[c] = __builtin_amdgcn_mfma_f32_16x16x32_f16(ah[kb], br, acc[c], 0, 0, 0);
      acc[c] = __builtin_amdgcn_mfma_f32_16x16x32_f16(ar[kb], bh, acc[c], 0, 0, 0);
    }
  }

  int r0 = gr0 + ks * 4;
  float dv[4];
#pragma unroll
  for (int i = 0; i < 4; ++i) dv[i] = (r0 + i < n) ? dinv[r0 + i] : 0.f;
#pragma unroll
  for (int c = 0; c < NCG; ++c) {
#pragma unroll
    for (int i = 0; i < 4; ++i) {
      int row = r0 + i;
      if (row < n) G[(size_t)row * DO + c * 16 + m] = __float2half(dv[i] * acc[c][i]);
    }
  }
}

// ---------------- aggregation ----------------

__device__ __forceinline__ float2 h2f(unsigned int u) {
  __half2 h = *(__half2*)&u;
  return __half22float2(h);
}

// wave per node, full 256B row per gather, 8 independent chains (deg~16 -> 2
// full unrolls in flight); writes split (h,r) pair for next layer's MFMA.
__global__ __launch_bounds__(256) void aggregate128(const unsigned int* __restrict__ G, const float* __restrict__ dinv,
                                                    const float* __restrict__ bias, const int* __restrict__ rp,
                                                    const int* __restrict__ col, unsigned int* __restrict__ Yh,
                                                    unsigned int* __restrict__ Yr, int n) {
  int v = (int)((blockIdx.x * 256 + threadIdx.x) >> 6);
  int lane = threadIdx.x & 63;
  if (v >= n) return;
  int s = rp[v], e = rp[v + 1];
  float2 a0 = h2f(G[(size_t)v * 64 + lane]);  // self-loop
  float2 a1 = make_float2(0.f, 0.f), a2 = make_float2(0.f, 0.f), a3 = make_float2(0.f, 0.f);
  float2 a4 = make_float2(0.f, 0.f), a5 = make_float2(0.f, 0.f);
  float2 a6 = make_float2(0.f, 0.f), a7 = make_float2(0.f, 0.f);
  int t = s;
  while (t < e) {
    int batch = e - t;
    if (batch > 64) batch = 64;
    int ci = col[t + (lane < batch ? lane : batch - 1)];
    int j = 0;
    for (; j + 8 <= batch; j += 8) {
      int u0 = __shfl(ci, j, 64), u1 = __shfl(ci, j + 1, 64);
      int u2 = __shfl(ci, j + 2, 64), u3 = __shfl(ci, j + 3, 64);
      int u4 = __shfl(ci, j + 4, 64), u5 = __shfl(ci, j + 5, 64);
      int u6 = __shfl(ci, j + 6, 64), u7 = __shfl(ci, j + 7, 64);
      unsigned int g0 = G[(size_t)u0 * 64 + lane];
      unsigned int g1 = G[(size_t)u1 * 64 + lane];
      unsigned int g2 = G[(size_t)u2 * 64 + lane];
      unsigned int g3 = G[(size_t)u3 * 64 + lane];
      unsigned int g4 = G[(size_t)u4 * 64 + lane];
      unsigned int g5 = G[(size_t)u5 * 64 + lane];
      unsigned int g6 = G[(size_t)u6 * 64 + lane];
      unsigned int g7 = G[(size_t)u7 * 64 + lane];
      float2 f0 = h2f(g0), f1 = h2f(g1), f2 = h2f(g2), f3 = h2f(g3);
      float2 f4 = h2f(g4), f5 = h2f(g5), f6 = h2f(g6), f7 = h2f(g7);
      a0.x += f0.x; a0.y += f0.y;
      a1.x += f1.x; a1.y += f1.y;
      a2.x += f2.x; a2.y += f2.y;
      a3.x += f3.x; a3.y += f3.y;
      a4.x += f4.x; a4.y += f4.y;
      a5.x += f5.x; a5.y += f5.y;
      a6.x += f6.x; a6.y += f6.y;
      a7.x += f7.x; a7.y += f7.y;
    }
    for (; j < batch; ++j) {
      int u = __shfl(ci, j, 64);
      float2 f = h2f(G[(size_t)u * 64 + lane]);
      a0.x += f.x; a0.y += f.y;
    }
    t += batch;
  }
  float sx = ((a0.x + a1.x) + (a2.x + a3.x)) + ((a4.x + a5.x) + (a6.x + a7.x));
  float sy = ((a0.y + a1.y) + (a2.y + a3.y)) + ((a4.y + a5.y) + (a6.y + a7.y));
  float dv = dinv[v];
  float2 bb = ((const float2*)bias)[lane];
  float ox = fmaxf(fmaf(dv, sx, bb.x), 0.f);  // ReLU
  float oy = fmaxf(fmaf(dv, sy, bb.y), 0.f);
  __half hx = __float2half(ox), hy = __float2half(oy);
  float rx = ox - __half2float(hx), ry = oy - __half2float(hy);
  __half rxh = __float2half(rx), ryh = __float2half(ry);
  size_t o = (size_t)v * 64 + lane;
  Yh[o] = ((unsigned int)*(unsigned short*)&hy << 16) | *(unsigned short*)&hx;
  Yr[o] = ((unsigned int)*(unsigned short*)&ryh << 16) | *(unsigned short*)&rxh;
}

__global__ __launch_bounds__(256) void aggregate64(const unsigned short* __restrict__ G, const float* __restrict__ dinv,
                                                   const float* __restrict__ bias, const int* __restrict__ rp,
                                                   const int* __restrict__ col, float* __restrict__ Y, int n) {
  int v = (int)((blockIdx.x * 256 + threadIdx.x) >> 6);
  int lane = threadIdx.x & 63;
  if (v >= n) return;
  int s = rp[v], e = rp[v + 1];
  float a0 = __half2float(*(const __half*)&G[(size_t)v * 64 + lane]);
  float a1 = 0.f, a2 = 0.f, a3 = 0.f;
  float a4 = 0.f, a5 = 0.f, a6 = 0.f, a7 = 0.f;
  int t = s;
  while (t < e) {
    int batch = e - t;
    if (batch > 64) batch = 64;
    int ci = col[t + (lane < batch ? lane : batch - 1)];
    int j = 0;
    for (; j + 8 <= batch; j += 8) {
      int u0 = __shfl(ci, j, 64), u1 = __shfl(ci, j + 1, 64);
      int u2 = __shfl(ci, j + 2, 64), u3 = __shfl(ci, j + 3, 64);
      int u4 = __shfl(ci, j + 4, 64), u5 = __shfl(ci, j + 5, 64);
      int u6 = __shfl(ci, j + 6, 64), u7 = __shfl(ci, j + 7, 64);
      unsigned short g0 = G[(size_t)u0 * 64 + lane];
      unsigned short g1 = G[(size_t)u1 * 64 + lane];
      unsigned short g2 = G[(size_t)u2 * 64 + lane];
      unsigned short g3 = G[(size_t)u3 * 64 + lane];
      unsigned short g4 = G[(size_t)u4 * 64 + lane];
      unsigned short g5 = G[(size_t)u5 * 64 + lane];
      unsigned short g6 = G[(size_t)u6 * 64 + lane];
      unsigned short g7 = G[(size_t)u7 * 64 + lane];
      a0 += __half2float(*(const __half*)&g0);
      a1 += __half2float(*(const __half*)&g1);
      a2 += __half2float(*(const __half*)&g2);
      a3 += __half2float(*(const __half*)&g3);
      a4 += __half2float(*(const __half*)&g4);
      a5 += __half2float(*(const __half*)&g5);
      a6 += __half2float(*(const __half*)&g6);
      a7 += __half2float(*(const __half*)&g7);
    }
    for (; j < batch; ++j) {
      int u = __shfl(ci, j, 64);
      unsigned short g = G[(size_t)u * 64 + lane];
      a0 += __half2float(*(const __half*)&g);
    }
    t += batch;
  }
  float sum = ((a0 + a1) + (a2 + a3)) + ((a4 + a5) + (a6 + a7));
  Y[(size_t)v * 64 + lane] = fmaf(dinv[v], sum, bias[lane]);
}

// ---------------- launch ----------------

extern "C" void kernel_launch(void* const* d_in, const int* in_sizes, int n_in,
                              void* d_out, int out_size, void* d_ws, size_t ws_size,
                              hipStream_t stream) {
  const float* x = (const float*)d_in[0];
  const void* ei = d_in[1];
  const int N = in_sizes[0] / 128;
  const int E = in_sizes[1] / 2;
  const float* W[5] = {(const float*)d_in[2], (const float*)d_in[4], (const float*)d_in[6],
                       (const float*)d_in[8], (const float*)d_in[10]};
  const float* B[5] = {(const float*)d_in[3], (const float*)d_in[5], (const float*)d_in[7],
                       (const float*)d_in[9], (const float*)d_in[11]};
  const int Wbin = (N + NBIN - 1) / NBIN;

  char* p = (char*)d_ws;
  unsigned short* xyh = (unsigned short*)p;  p += (size_t)N * 128 * 2;   // activations h
  unsigned short* xyr = (unsigned short*)p;  p += (size_t)N * 128 * 2;   // activations r
  __half* g = (__half*)p;                    p += (size_t)N * 128 * 2;   // post-GEMM dinv.*h
  uint2* ebin = (uint2*)g;                   // ALIAS: ebin dead before first gemm writes g
  unsigned short* wh = (unsigned short*)p;   p += (size_t)5 * 16384 * 2;
  unsigned short* wr = (unsigned short*)p;   p += (size_t)5 * 16384 * 2;
  float* dinv = (float*)p;                   p += (size_t)N * 4;
  int* col = (int*)p;                        p += (size_t)E * 4;
  int* row_ptr = (int*)p;                    p += (size_t)(N + 1) * 4;
  int* bcnt = (int*)p;                       p += (size_t)NB * NBIN * 4;
  int* bintot = (int*)p;                     p += NBIN * 4;

  k_cnt2<<<NB, 512, 0, stream>>>(ei, bcnt, E, N, Wbin);
  k_scanb<<<NBIN, 256, 0, stream>>>(bcnt, bintot);
  k_scat<<<NB, 512, 0, stream>>>(ei, bintot, bcnt, ebin, E, N, Wbin);
  k_build<<<NBIN, 256, 0, stream>>>(ebin, bintot, row_ptr, dinv, col, N, Wbin);

  k_split_x<<<(N * 64 + 255) / 256, 256, 0, stream>>>(x, (unsigned int*)xyh, (unsigned int*)xyr, N * 64);
  k_split_wall<<<(73728 + 255) / 256, 256, 0, stream>>>(W[0], W[1], W[2], W[3], W[4], wh, wr, 73728);

  const int gb = (N + 63) / 64;
  const int ab = (N * 64 + 255) / 256;

  for (int l = 0; l < 4; ++l) {
    gemm_mfma<128><<<gb, 256, 0, stream>>>(xyh, xyr, wh + l * 16384, wr + l * 16384, dinv, g, N);
    aggregate128<<<ab, 256, 0, stream>>>((const unsigned int*)g, dinv, B[l], row_ptr, col,
                                         (unsigned int*)xyh, (unsigned int*)xyr, N);
  }
  gemm_mfma<64><<<gb, 256, 0, stream>>>(xyh, xyr, wh + 4 * 16384, wr + 4 * 16384, dinv, g, N);
  aggregate64<<<ab, 256, 0, stream>>>((const unsigned short*)g, dinv, B[4], row_ptr, col, (float*)d_out, N);
}